// Round 10
// baseline (4386.623 us; speedup 1.0000x reference)
//
#include <hip/hip_runtime.h>
#include <stdint.h>

// ---------------- problem constants ----------------
#define EDIM   300      // hidden/embed dim
#define KPAD   320      // padded K for MFMA GEMMs
#define NG     1200     // 4*EDIM gates
#define NB     64       // batch
#define SENC   64       // encoder steps
#define SDEC   63       // decoder steps
#define ZHV    12016
#define DROWS  4032     // NB*SDEC
#define MPAD   4096

typedef unsigned short u16;
typedef __attribute__((ext_vector_type(8))) short bf16x8;
typedef __attribute__((ext_vector_type(4))) float f32x4;

static __device__ __forceinline__ u16 f2bf(float f){
  uint32_t u = __builtin_bit_cast(uint32_t, f);
  return (u16)((u + 0x7fffu + ((u >> 16) & 1u)) >> 16);
}
static __device__ __forceinline__ float sigm(float x){ return 1.f/(1.f + __expf(-x)); }
static __device__ __forceinline__ float tanhf_(float x){
  x = fminf(fmaxf(x, -15.f), 15.f);
  float e = __expf(2.f*x);
  return (e - 1.f)/(e + 1.f);
}

// ---------------- workspace init ----------------
__global__ void zero_kernel(float4* p, long n){
  long i = (long)blockIdx.x*blockDim.x + threadIdx.x;
  long st = (long)gridDim.x*blockDim.x;
  float4 z = {0.f,0.f,0.f,0.f};
  for (; i < n; i += st) p[i] = z;
}

// ---------------- Whh (1200x300) f32 -> MFMA A-fragment tiles bf16 ----------------
// frag = ((slice*4 + gate)*10 + kc); elem (lane*8 + e) = Whh[g*300 + slice*16 + (lane&15)]
//                                                          [kc*32 + (lane>>4)*8 + e], 0-padded.
__global__ void build_wa(const float* __restrict__ W, u16* __restrict__ out){
  int idx = blockIdx.x*blockDim.x + threadIdx.x;
  if (idx >= 20*4*10*512) return;
  int e    = idx & 7;
  int lane = (idx >> 3) & 63;
  int frag = idx >> 9;
  int kc = frag % 10;
  int g  = (frag / 10) & 3;
  int s  = frag / 40;
  int j = s*16 + (lane & 15);
  int k = kc*32 + ((lane >> 4) << 3) + e;
  float f = (j < EDIM && k < EDIM) ? W[(size_t)(g*EDIM + j)*EDIM + k] : 0.f;
  out[idx] = f2bf(f);
}

// ---------------- weight repack: (N x 300) f32 -> (Npad x 320) bf16 ----------------
__global__ void build_b(const float* __restrict__ W, u16* __restrict__ out, int N){
  int idx = blockIdx.x*blockDim.x + threadIdx.x;
  if (idx >= N*EDIM) return;
  int n = idx / EDIM, k = idx - n*EDIM;
  out[(size_t)n*KPAD + k] = f2bf(W[idx]);
}

// ---------------- embeddings -> padded bf16 A operands ----------------
__global__ void embed_en(const int* __restrict__ ids, const float* __restrict__ emb, u16* __restrict__ x){
  int idx = blockIdx.x*blockDim.x + threadIdx.x;
  if (idx >= MPAD*EDIM) return;
  int r = idx / EDIM, k = idx - r*EDIM;
  x[(size_t)r*KPAD + k] = f2bf(emb[(size_t)ids[r]*EDIM + k]);
}
__global__ void embed_zh(const int* __restrict__ zh, const float* __restrict__ emb, u16* __restrict__ x){
  int idx = blockIdx.x*blockDim.x + threadIdx.x;
  if (idx >= DROWS*EDIM) return;
  int r = idx / EDIM, k = idx - r*EDIM;
  int b = r / SDEC, t = r - b*SDEC;
  x[(size_t)r*KPAD + k] = f2bf(emb[(size_t)zh[b*SENC + t]*EDIM + k]);
}

// ---------------- bf16 MFMA GEMM: C[m,n] = sum_k A[m,k]*B[n,k] (+bias[n]) ----------------
#define LDT 40   // LDS row stride in bf16 elems (80 B)
__global__ __launch_bounds__(256) void gemm_nt(const u16* __restrict__ A, const u16* __restrict__ B,
                float* __restrict__ C, int ldc, int Mreal, int Nreal, const float* __restrict__ bias){
  __shared__ __align__(16) u16 As[128*LDT];
  __shared__ __align__(16) u16 Bs[128*LDT];
  int tid = threadIdx.x;
  int lane = tid & 63, wave = tid >> 6;
  int wm = wave >> 1, wn = wave & 1;
  int m0 = blockIdx.y*128, n0 = blockIdx.x*128;
  f32x4 acc[4][4];
  for (int i=0;i<4;i++) for (int j=0;j<4;j++) acc[i][j] = (f32x4){0.f,0.f,0.f,0.f};
  int r16 = lane & 15, kg = lane >> 4;
  for (int kt=0; kt<KPAD/32; kt++){
    int k0 = kt*32;
    for (int c=0;c<2;c++){
      int id = c*256 + tid;            // 0..511
      int row = id >> 2, col = id & 3; // 4 x 16B chunks per 32-k row
      *(uint4*)&As[row*LDT + col*8] = *(const uint4*)&A[(size_t)(m0+row)*KPAD + k0 + col*8];
      *(uint4*)&Bs[row*LDT + col*8] = *(const uint4*)&B[(size_t)(n0+row)*KPAD + k0 + col*8];
    }
    __syncthreads();
    bf16x8 af[4], bfr[4];
    for (int i=0;i<4;i++) af[i]  = *(const bf16x8*)&As[(wm*64 + i*16 + r16)*LDT + kg*8];
    for (int j=0;j<4;j++) bfr[j] = *(const bf16x8*)&Bs[(wn*64 + j*16 + r16)*LDT + kg*8];
    for (int i=0;i<4;i++)
      for (int j=0;j<4;j++)
        acc[i][j] = __builtin_amdgcn_mfma_f32_16x16x32_bf16(af[i], bfr[j], acc[i][j], 0, 0, 0);
    __syncthreads();
  }
  // C/D layout (m89-verified): col = lane&15, row = (lane>>4)*4 + reg
  for (int j=0;j<4;j++){
    int col = n0 + wn*64 + j*16 + r16;
    if (col >= Nreal) continue;
    float bv = bias ? bias[col] : 0.f;
    for (int i=0;i<4;i++){
      int rbase = m0 + wm*64 + i*16 + kg*4;
      for (int r=0;r<4;r++){
        int row = rbase + r;
        if (row < Mreal) C[(size_t)row*ldc + col] = acc[i][j][r] + bv;
      }
    }
  }
}

// ---------------- LSTM recurrence: row-parallel, 3-tier, spill-proof shape ----------------
// 4 blocks x 256 thr (4 waves, 1 wave/SIMD -> 512 VGPR cap; the R5-proven no-spill
// compilation shape). Block rg owns rows [16rg,16rg+16): zero inter-block traffic,
// ONE barrier/step. Weight tiers: slices 0..7 register-resident (wave w holds
// slices {2w, 2w+1} = 320 VGPR); slices 8..10 in LDS (120 KB, staged once);
// slices 11..18 streamed from L2 (wave w: {11+2w, 12+2w}; 320 KB/step/CU ~= the
// 2.8us/step port floor). Streamed kc loops use unroll(2) to bound in-flight
// load batching (~32 VGPRs) — R9's spill came from ~160-reg load batching.
// h double-buffered in LDS (XOR-swizzled); activation lane-local.
__global__ __launch_bounds__(256,1) void recur_t3(
    const float* __restrict__ Xih, const u16* __restrict__ WA,
    const float* __restrict__ h0, const float* __restrict__ c0,
    u16* seq, float* hfin, float* cfin, int steps)
{
  int tid = threadIdx.x;
  int lane = tid & 63, w = tid >> 6;     // wave 0..3
  int rg = blockIdx.x;
  int l15 = lane & 15, lk = lane >> 4;
  int row = rg*16 + l15;

  __shared__ __align__(16) u16 hb[2][16*320];      // h double buffer, XOR-swizzled rows
  __shared__ __align__(16) u16 wl[3][4][10][512];  // LDS slices 8..10

  // stage LDS weight slices (frags 320..439 contiguous in WA)
  {
    const uint4* src = (const uint4*)(WA + (size_t)320*512);
    uint4* dst = (uint4*)wl;
    for (int i = tid; i < 7680; i += 256) dst[i] = src[i];
  }
  // zero both h buffers (pad k>=300 must stay 0)
  for (int i=tid; i<2*16*160; i+=256) ((uint32_t*)hb)[i] = 0;

  // resident slices 2w, 2w+1: 320 VGPR
  int sA = 2*w, sB = 2*w + 1;
  bf16x8 wfA[4][10], wfB[4][10];
  #pragma unroll
  for (int g=0; g<4; ++g)
    #pragma unroll
    for (int kc=0; kc<10; ++kc){
      wfA[g][kc] = *(const bf16x8*)&WA[(size_t)((sA*4+g)*10+kc)*512 + lane*8];
      wfB[g][kc] = *(const bf16x8*)&WA[(size_t)((sB*4+g)*10+kc)*512 + lane*8];
    }

  // j bases and lane-local c state
  int jA = sA*16 + lk*4;          // 0..123, real
  int jB = sB*16 + lk*4;          // 16..127, real
  int jL = (8+w)*16 + lk*4;       // 128..175 (waves 0..2), real
  int s1 = 11 + 2*w, s2 = 12 + 2*w;
  int j1 = s1*16 + lk*4;          // 176..287, real
  int j2 = s2*16 + lk*4;          // 192..303 (j==300 masked)
  f32x4 cA = *(const f32x4*)&c0[row*EDIM + jA];
  f32x4 cB = *(const f32x4*)&c0[row*EDIM + jB];
  f32x4 c1 = *(const f32x4*)&c0[row*EDIM + j1];
  f32x4 c2 = (f32x4){0.f,0.f,0.f,0.f};
  f32x4 cL = (f32x4){0.f,0.f,0.f,0.f};
  if (j2 < EDIM) c2 = *(const f32x4*)&c0[row*EDIM + j2];
  if (w < 3)     cL = *(const f32x4*)&c0[row*EDIM + jL];

  __syncthreads();
  // stage h0 into buffer 0
  for (int i=tid; i<16*150; i+=256){
    int rw = i/150, jp = i - rw*150;
    float a = h0[(size_t)(rg*16+rw)*EDIM + jp*2];
    float b = h0[(size_t)(rg*16+rw)*EDIM + jp*2 + 1];
    uint32_t pk = (uint32_t)f2bf(a) | ((uint32_t)f2bf(b) << 16);
    *(uint32_t*)((char*)hb + rw*640 + ((jp*4) ^ ((rw&7)<<4))) = pk;
  }
  __syncthreads();

  for (int t=0; t<steps; ++t){
    const char* hcur = (const char*)hb + (t&1)*10240;
    char* hnxt = (char*)hb + (((t&1)^1))*10240;
    const float* xr = Xih + (size_t)(row*steps + t)*NG;

#define ACT_PUB(ACC, CV, J)                                                        \
    {                                                                              \
      float hv0_, hv1_, hv2_, hv3_;                                                \
      { float c_ = sigm(ACC[1][0])*CV[0] + sigm(ACC[0][0])*tanhf_(ACC[2][0]);      \
        CV[0] = c_; hv0_ = sigm(ACC[3][0])*tanhf_(c_); }                           \
      { float c_ = sigm(ACC[1][1])*CV[1] + sigm(ACC[0][1])*tanhf_(ACC[2][1]);      \
        CV[1] = c_; hv1_ = sigm(ACC[3][1])*tanhf_(c_); }                           \
      { float c_ = sigm(ACC[1][2])*CV[2] + sigm(ACC[0][2])*tanhf_(ACC[2][2]);      \
        CV[2] = c_; hv2_ = sigm(ACC[3][2])*tanhf_(c_); }                           \
      { float c_ = sigm(ACC[1][3])*CV[3] + sigm(ACC[0][3])*tanhf_(ACC[2][3]);      \
        CV[3] = c_; hv3_ = sigm(ACC[3][3])*tanhf_(c_); }                           \
      if ((J) < EDIM){                                                             \
        uint2 q_;                                                                  \
        q_.x = (uint32_t)f2bf(hv0_) | ((uint32_t)f2bf(hv1_)<<16);                  \
        q_.y = (uint32_t)f2bf(hv2_) | ((uint32_t)f2bf(hv3_)<<16);                  \
        *(uint2*)(hnxt + l15*640 + (((J)*2) ^ ((l15&7)<<4))) = q_;                 \
        if (seq) *(uint2*)&seq[(size_t)(row*steps+t)*KPAD + (J)] = q_;             \
        if (t == steps-1 && hfin){                                                 \
          *(f32x4*)&hfin[row*EDIM + (J)] = (f32x4){hv0_,hv1_,hv2_,hv3_};           \
          *(f32x4*)&cfin[row*EDIM + (J)] = CV;                                     \
        }                                                                          \
      }                                                                            \
    }

    // ---- streamed slice 1 (L2). unroll(2) bounds in-flight weight regs.
    {
      f32x4 acc[4];
      #pragma unroll
      for (int g=0; g<4; ++g) acc[g] = *(const f32x4*)&xr[g*EDIM + j1];
      const u16* wb = WA + (size_t)(s1*40)*512 + lane*8;
      #pragma unroll 2
      for (int kc=0; kc<10; ++kc){
        bf16x8 hf = *(const bf16x8*)(hcur + l15*640 + (((kc*64) + lk*16) ^ ((l15&7)<<4)));
        #pragma unroll
        for (int g=0; g<4; ++g)
          acc[g] = __builtin_amdgcn_mfma_f32_16x16x32_bf16(
                     *(const bf16x8*)&wb[(size_t)(g*10+kc)*512], hf, acc[g], 0, 0, 0);
      }
      ACT_PUB(acc, c1, j1)
    }
    // ---- resident slice A (pure reg/LDS; covers latency of streamed slice 2 issue)
    {
      f32x4 acc[4];
      #pragma unroll
      for (int g=0; g<4; ++g) acc[g] = *(const f32x4*)&xr[g*EDIM + jA];
      #pragma unroll
      for (int kc=0; kc<10; ++kc){
        bf16x8 hf = *(const bf16x8*)(hcur + l15*640 + (((kc*64) + lk*16) ^ ((l15&7)<<4)));
        #pragma unroll
        for (int g=0; g<4; ++g)
          acc[g] = __builtin_amdgcn_mfma_f32_16x16x32_bf16(wfA[g][kc], hf, acc[g], 0, 0, 0);
      }
      ACT_PUB(acc, cA, jA)
    }
    // ---- streamed slice 2
    {
      f32x4 acc[4];
      #pragma unroll
      for (int g=0; g<4; ++g) acc[g] = *(const f32x4*)&xr[g*EDIM + j2];
      const u16* wb = WA + (size_t)(s2*40)*512 + lane*8;
      #pragma unroll 2
      for (int kc=0; kc<10; ++kc){
        bf16x8 hf = *(const bf16x8*)(hcur + l15*640 + (((kc*64) + lk*16) ^ ((l15&7)<<4)));
        #pragma unroll
        for (int g=0; g<4; ++g)
          acc[g] = __builtin_amdgcn_mfma_f32_16x16x32_bf16(
                     *(const bf16x8*)&wb[(size_t)(g*10+kc)*512], hf, acc[g], 0, 0, 0);
      }
      ACT_PUB(acc, c2, j2)
    }
    // ---- resident slice B
    {
      f32x4 acc[4];
      #pragma unroll
      for (int g=0; g<4; ++g) acc[g] = *(const f32x4*)&xr[g*EDIM + jB];
      #pragma unroll
      for (int kc=0; kc<10; ++kc){
        bf16x8 hf = *(const bf16x8*)(hcur + l15*640 + (((kc*64) + lk*16) ^ ((l15&7)<<4)));
        #pragma unroll
        for (int g=0; g<4; ++g)
          acc[g] = __builtin_amdgcn_mfma_f32_16x16x32_bf16(wfB[g][kc], hf, acc[g], 0, 0, 0);
      }
      ACT_PUB(acc, cB, jB)
    }
    // ---- LDS slice (waves 0..2)
    if (w < 3){
      f32x4 acc[4];
      #pragma unroll
      for (int g=0; g<4; ++g) acc[g] = *(const f32x4*)&xr[g*EDIM + jL];
      #pragma unroll
      for (int kc=0; kc<10; ++kc){
        bf16x8 hf = *(const bf16x8*)(hcur + l15*640 + (((kc*64) + lk*16) ^ ((l15&7)<<4)));
        #pragma unroll
        for (int g=0; g<4; ++g)
          acc[g] = __builtin_amdgcn_mfma_f32_16x16x32_bf16(
                     *(const bf16x8*)&wl[w][g][kc][lane*8], hf, acc[g], 0, 0, 0);
      }
      ACT_PUB(acc, cL, jL)
    }
#undef ACT_PUB
    __syncthreads();   // h(t) complete in hnxt before next step's reads
  }
}

// ---------------- fused log_softmax (in-place on d_out) + masked NLL ----------------
__global__ __launch_bounds__(256) void lsm_loss(float* __restrict__ out, const int* __restrict__ zh,
                                                float* __restrict__ lacc){
  int row = blockIdx.x;
  int tid = threadIdx.x;
  __shared__ float buf[ZHV];
  __shared__ float red[8];
  float* p = out + (size_t)row*ZHV;
  float m = -1e30f;
  for (int i=tid; i<ZHV; i+=256){ float v = p[i]; buf[i] = v; m = fmaxf(m, v); }
  for (int off=32; off; off>>=1) m = fmaxf(m, __shfl_xor(m, off));
  if ((tid&63)==0) red[tid>>6] = m;
  __syncthreads();
  m = fmaxf(fmaxf(red[0],red[1]), fmaxf(red[2],red[3]));
  float s = 0.f;
  for (int i=tid; i<ZHV; i+=256) s += __expf(buf[i]-m);
  for (int off=32; off; off>>=1) s += __shfl_xor(s, off);
  if ((tid&63)==0) red[4+(tid>>6)] = s;
  __syncthreads();
  s = red[4]+red[5]+red[6]+red[7];
  float lse = m + __logf(s);
  for (int i=tid; i<ZHV; i+=256) p[i] = buf[i] - lse;
  if (tid == 0){
    int b = row / SDEC, t = row - b*SDEC;
    int tgt = zh[b*SENC + t + 1];
    if (tgt != 0){
      atomicAdd(&lacc[0], -(buf[tgt] - lse));
      atomicAdd(&lacc[1], 1.0f);
    }
  }
}

__global__ void fin_loss(float* out, const float* lacc){
  out[(size_t)DROWS*ZHV] = lacc[0]/lacc[1];
}

// ---------------- host ----------------
extern "C" void kernel_launch(void* const* d_in, const int* in_sizes, int n_in,
                              void* d_out, int out_size, void* d_ws, size_t ws_size,
                              hipStream_t stream){
  const int*   en_in   = (const int*)d_in[0];
  const int*   zh_in   = (const int*)d_in[1];
  const float* en_emb  = (const float*)d_in[2];
  const float* zh_emb  = (const float*)d_in[3];
  const float* enc_Wih = (const float*)d_in[4];
  const float* enc_Whh = (const float*)d_in[5];
  const float* enc_b   = (const float*)d_in[6];
  const float* dec_Wih = (const float*)d_in[7];
  const float* dec_Whh = (const float*)d_in[8];
  const float* dec_b   = (const float*)d_in[9];
  const float* fc_W    = (const float*)d_in[10];
  const float* fc_b    = (const float*)d_in[11];
  float* out = (float*)d_out;
  char* ws = (char*)d_ws;

  size_t o = 0;
  auto alloc = [&](size_t b){ size_t r = o; o = (o + b + 255) & ~(size_t)255; return r; };
  size_t wa[4], wih[4];
  for (int i=0;i<4;i++) wa[i]  = alloc((size_t)20*4*10*512*2); // MFMA A-frag Whh bf16
  for (int i=0;i<4;i++) wih[i] = alloc((size_t)1280*KPAD*2);   // Wih as B operand
  size_t fcw  = alloc((size_t)12032*KPAD*2);
  size_t xen  = alloc((size_t)MPAD*KPAD*2);
  size_t xl1e = alloc((size_t)MPAD*KPAD*2);
  size_t xzh  = alloc((size_t)MPAD*KPAD*2);
  size_t xl1d = alloc((size_t)MPAD*KPAD*2);
  size_t xl2d = alloc((size_t)MPAD*KPAD*2);
  size_t xih  = alloc(((size_t)MPAD*NG + 64)*4);   // +64 floats: padded-slice overread
  size_t hfin = alloc((size_t)2*NB*EDIM*4);
  size_t cfin = alloc((size_t)2*NB*EDIM*4);
  size_t hz   = alloc((size_t)NB*EDIM*4 + 64);
  size_t lac  = alloc(256);
  size_t used = o;
  if (ws_size < used) return;  // fail loudly (output stays poisoned)

  zero_kernel<<<2048,256,0,stream>>>((float4*)ws, (long)(used/16));

  for (int l=0;l<2;l++){
    build_wa<<<1600,256,0,stream>>>(enc_Whh + (size_t)l*NG*EDIM, (u16*)(ws+wa[l]));
    build_wa<<<1600,256,0,stream>>>(dec_Whh + (size_t)l*NG*EDIM, (u16*)(ws+wa[2+l]));
    build_b<<<1407,256,0,stream>>>(enc_Wih + (size_t)l*NG*EDIM, (u16*)(ws+wih[l]),   NG);
    build_b<<<1407,256,0,stream>>>(dec_Wih + (size_t)l*NG*EDIM, (u16*)(ws+wih[2+l]), NG);
  }
  build_b<<<(ZHV*EDIM+255)/256,256,0,stream>>>(fc_W, (u16*)(ws+fcw), ZHV);
  embed_en<<<(MPAD*EDIM+255)/256,256,0,stream>>>(en_in, en_emb, (u16*)(ws+xen));
  embed_zh<<<(DROWS*EDIM+255)/256,256,0,stream>>>(zh_in, zh_emb, (u16*)(ws+xzh));

  float* XIH = (float*)(ws+xih);
  float* LAC = (float*)(ws+lac);
  float* HF  = (float*)(ws+hfin);
  float* CF  = (float*)(ws+cfin);
  float* HZ  = (float*)(ws+hz);

  // encoder layer 1  (LSTM bias folded into XIH via gemm bias)
  gemm_nt<<<dim3(10,32),256,0,stream>>>((u16*)(ws+xen), (u16*)(ws+wih[0]), XIH, NG, MPAD, NG, enc_b);
  recur_t3<<<4,256,0,stream>>>(XIH, (u16*)(ws+wa[0]), HZ, HZ, (u16*)(ws+xl1e), HF, CF, SENC);
  // encoder layer 2 (hidden sequence unused; only finals kept)
  gemm_nt<<<dim3(10,32),256,0,stream>>>((u16*)(ws+xl1e), (u16*)(ws+wih[1]), XIH, NG, MPAD, NG, enc_b+NG);
  recur_t3<<<4,256,0,stream>>>(XIH, (u16*)(ws+wa[1]), HZ, HZ, nullptr, HF+NB*EDIM, CF+NB*EDIM, SENC);
  // decoder layer 1
  gemm_nt<<<dim3(10,32),256,0,stream>>>((u16*)(ws+xzh), (u16*)(ws+wih[2]), XIH, NG, MPAD, NG, dec_b);
  recur_t3<<<4,256,0,stream>>>(XIH, (u16*)(ws+wa[2]), HF, CF, (u16*)(ws+xl1d), nullptr, nullptr, SDEC);
  // decoder layer 2
  gemm_nt<<<dim3(10,32),256,0,stream>>>((u16*)(ws+xl1d), (u16*)(ws+wih[3]), XIH, NG, MPAD, NG, dec_b+NG);
  recur_t3<<<4,256,0,stream>>>(XIH, (u16*)(ws+wa[3]), HF+NB*EDIM, CF+NB*EDIM, (u16*)(ws+xl2d), nullptr, nullptr, SDEC);
  // FC head -> logits straight into d_out
  gemm_nt<<<dim3(94,32),256,0,stream>>>((u16*)(ws+xl2d), (u16*)(ws+fcw), out, ZHV, DROWS, ZHV, fc_b);
  // in-place log_softmax + masked NLL
  lsm_loss<<<DROWS,256,0,stream>>>(out, zh_in, LAC);
  fin_loss<<<1,1,0,stream>>>(out, LAC);
}

// Round 11
// 2800.808 us; speedup vs baseline: 1.5662x; 1.5662x over previous
//
#include <hip/hip_runtime.h>
#include <stdint.h>

// ---------------- problem constants ----------------
#define EDIM   300      // hidden/embed dim
#define KPAD   320      // padded K for MFMA GEMMs
#define NG     1200     // 4*EDIM gates
#define NB     64       // batch
#define SENC   64       // encoder steps
#define SDEC   63       // decoder steps
#define ZHV    12016
#define DROWS  4032     // NB*SDEC
#define MPAD   4096

typedef unsigned short u16;
typedef __attribute__((ext_vector_type(8))) short bf16x8;
typedef __attribute__((ext_vector_type(4))) float f32x4;

static __device__ __forceinline__ u16 f2bf(float f){
  uint32_t u = __builtin_bit_cast(uint32_t, f);
  return (u16)((u + 0x7fffu + ((u >> 16) & 1u)) >> 16);
}
static __device__ __forceinline__ float sigm(float x){ return 1.f/(1.f + __expf(-x)); }
static __device__ __forceinline__ float tanhf_(float x){
  x = fminf(fmaxf(x, -15.f), 15.f);
  float e = __expf(2.f*x);
  return (e - 1.f)/(e + 1.f);
}

// ---------------- workspace init ----------------
__global__ void zero_kernel(float4* p, long n){
  long i = (long)blockIdx.x*blockDim.x + threadIdx.x;
  long st = (long)gridDim.x*blockDim.x;
  float4 z = {0.f,0.f,0.f,0.f};
  for (; i < n; i += st) p[i] = z;
}

// ---------------- Whh (1200x300) f32 -> MFMA A-fragment tiles bf16 ----------------
// frag = ((slice*4 + gate)*10 + kc); elem (lane*8 + e) = Whh[g*300 + slice*16 + (lane&15)]
//                                                          [kc*32 + (lane>>4)*8 + e], 0-padded.
__global__ void build_wa(const float* __restrict__ W, u16* __restrict__ out){
  int idx = blockIdx.x*blockDim.x + threadIdx.x;
  if (idx >= 20*4*10*512) return;
  int e    = idx & 7;
  int lane = (idx >> 3) & 63;
  int frag = idx >> 9;
  int kc = frag % 10;
  int g  = (frag / 10) & 3;
  int s  = frag / 40;
  int j = s*16 + (lane & 15);
  int k = kc*32 + ((lane >> 4) << 3) + e;
  float f = (j < EDIM && k < EDIM) ? W[(size_t)(g*EDIM + j)*EDIM + k] : 0.f;
  out[idx] = f2bf(f);
}

// ---------------- weight repack: (N x 300) f32 -> (Npad x 320) bf16 ----------------
__global__ void build_b(const float* __restrict__ W, u16* __restrict__ out, int N){
  int idx = blockIdx.x*blockDim.x + threadIdx.x;
  if (idx >= N*EDIM) return;
  int n = idx / EDIM, k = idx - n*EDIM;
  out[(size_t)n*KPAD + k] = f2bf(W[idx]);
}

// ---------------- embeddings -> padded bf16 A operands ----------------
__global__ void embed_en(const int* __restrict__ ids, const float* __restrict__ emb, u16* __restrict__ x){
  int idx = blockIdx.x*blockDim.x + threadIdx.x;
  if (idx >= MPAD*EDIM) return;
  int r = idx / EDIM, k = idx - r*EDIM;
  x[(size_t)r*KPAD + k] = f2bf(emb[(size_t)ids[r]*EDIM + k]);
}
__global__ void embed_zh(const int* __restrict__ zh, const float* __restrict__ emb, u16* __restrict__ x){
  int idx = blockIdx.x*blockDim.x + threadIdx.x;
  if (idx >= DROWS*EDIM) return;
  int r = idx / EDIM, k = idx - r*EDIM;
  int b = r / SDEC, t = r - b*SDEC;
  x[(size_t)r*KPAD + k] = f2bf(emb[(size_t)zh[b*SENC + t]*EDIM + k]);
}

// ---------------- bf16 MFMA GEMM: C[m,n] = sum_k A[m,k]*B[n,k] (+bias[n]) ----------------
#define LDT 40   // LDS row stride in bf16 elems (80 B)
__global__ __launch_bounds__(256) void gemm_nt(const u16* __restrict__ A, const u16* __restrict__ B,
                float* __restrict__ C, int ldc, int Mreal, int Nreal, const float* __restrict__ bias){
  __shared__ __align__(16) u16 As[128*LDT];
  __shared__ __align__(16) u16 Bs[128*LDT];
  int tid = threadIdx.x;
  int lane = tid & 63, wave = tid >> 6;
  int wm = wave >> 1, wn = wave & 1;
  int m0 = blockIdx.y*128, n0 = blockIdx.x*128;
  f32x4 acc[4][4];
  for (int i=0;i<4;i++) for (int j=0;j<4;j++) acc[i][j] = (f32x4){0.f,0.f,0.f,0.f};
  int r16 = lane & 15, kg = lane >> 4;
  for (int kt=0; kt<KPAD/32; kt++){
    int k0 = kt*32;
    for (int c=0;c<2;c++){
      int id = c*256 + tid;            // 0..511
      int row = id >> 2, col = id & 3; // 4 x 16B chunks per 32-k row
      *(uint4*)&As[row*LDT + col*8] = *(const uint4*)&A[(size_t)(m0+row)*KPAD + k0 + col*8];
      *(uint4*)&Bs[row*LDT + col*8] = *(const uint4*)&B[(size_t)(n0+row)*KPAD + k0 + col*8];
    }
    __syncthreads();
    bf16x8 af[4], bfr[4];
    for (int i=0;i<4;i++) af[i]  = *(const bf16x8*)&As[(wm*64 + i*16 + r16)*LDT + kg*8];
    for (int j=0;j<4;j++) bfr[j] = *(const bf16x8*)&Bs[(wn*64 + j*16 + r16)*LDT + kg*8];
    for (int i=0;i<4;i++)
      for (int j=0;j<4;j++)
        acc[i][j] = __builtin_amdgcn_mfma_f32_16x16x32_bf16(af[i], bfr[j], acc[i][j], 0, 0, 0);
    __syncthreads();
  }
  // C/D layout (m89-verified): col = lane&15, row = (lane>>4)*4 + reg
  for (int j=0;j<4;j++){
    int col = n0 + wn*64 + j*16 + r16;
    if (col >= Nreal) continue;
    float bv = bias ? bias[col] : 0.f;
    for (int i=0;i<4;i++){
      int rbase = m0 + wm*64 + i*16 + kg*4;
      for (int r=0;r<4;r++){
        int row = rbase + r;
        if (row < Mreal) C[(size_t)row*ldc + col] = acc[i][j][r] + bv;
      }
    }
  }
}

// ---------------- LSTM recurrence: row-parallel, 3-tier, 256-VGPR-honest ----------------
// HW fact (R10 post-mortem): per-SIMD regfile = 512 regs; at 2 waves/SIMD each wave
// gets at most 256 (VGPR+AGPR combined). Any plan demanding >256/wave spills.
// R9 spilled because its fully-unrolled streamed loop batched 40 loads = 160 in-flight
// regs on top of 160 resident. Fix: unroll(2) bounds in-flight to ~32.
// Shape: 4 blocks x 512 thr (8 waves, 1 block/CU, 2 waves/SIMD — TLP hides L2 lat).
// Block rg owns rows [16rg,16rg+16): zero inter-block traffic, ONE barrier/step.
// Tiers: slices 0..7 register-resident (wave w holds slice w: 160 VGPR); slices
// 8..10 in LDS (120 KB, staged once); slices 11..18 streamed from L2 (320 KB/step/CU
// ~2.4us port floor — the explicit bottleneck). Demand/wave ~= 160+16+32+12+20 ~ 240.
// h double-buffered in LDS (XOR-swizzled); activation lane-local (C: col=row, row=j).
__global__ __launch_bounds__(512,2) void recur_mix(
    const float* __restrict__ Xih, const u16* __restrict__ WA,
    const float* __restrict__ h0, const float* __restrict__ c0,
    u16* seq, float* hfin, float* cfin, int steps)
{
  int tid = threadIdx.x;
  int lane = tid & 63, w = tid >> 6;
  int rg = blockIdx.x;
  int l15 = lane & 15, lk = lane >> 4;
  int row = rg*16 + l15;

  __shared__ __align__(16) u16 hb[2][16*320];      // h double buffer, XOR-swizzled rows
  __shared__ __align__(16) u16 wl[3][4][10][512];  // LDS slices 8..10

  // stage LDS weight slices (frags 320..439 contiguous in WA)
  {
    const uint4* src = (const uint4*)(WA + (size_t)320*512);
    uint4* dst = (uint4*)wl;
    for (int i = tid; i < 7680; i += 512) dst[i] = src[i];
  }
  // zero both h buffers (pad k>=300 must stay 0)
  for (int i=tid; i<2*16*160; i+=512) ((uint32_t*)hb)[i] = 0;

  // resident slice w: 160 VGPR (R5-proven size)
  bf16x8 wf[4][10];
  #pragma unroll
  for (int g=0; g<4; ++g)
    #pragma unroll
    for (int kc=0; kc<10; ++kc)
      wf[g][kc] = *(const bf16x8*)&WA[(size_t)((w*4+g)*10+kc)*512 + lane*8];

  // per-slice j bases and c state (lane-local forever)
  int jR = w*16 + lk*4;          // < 128, always real
  int jS = (11+w)*16 + lk*4;     // 176..303 (j==300 masked)
  int jL = (8+w)*16 + lk*4;      // 128..175 (waves 0..2)
  f32x4 cR = *(const f32x4*)&c0[row*EDIM + jR];
  f32x4 cS = (f32x4){0.f,0.f,0.f,0.f};
  f32x4 cL = (f32x4){0.f,0.f,0.f,0.f};
  if (jS < EDIM) cS = *(const f32x4*)&c0[row*EDIM + jS];
  if (w < 3)     cL = *(const f32x4*)&c0[row*EDIM + jL];

  __syncthreads();
  // stage h0 into buffer 0
  for (int i=tid; i<16*150; i+=512){
    int rw = i/150, jp = i - rw*150;
    float a = h0[(size_t)(rg*16+rw)*EDIM + jp*2];
    float b = h0[(size_t)(rg*16+rw)*EDIM + jp*2 + 1];
    uint32_t pk = (uint32_t)f2bf(a) | ((uint32_t)f2bf(b) << 16);
    *(uint32_t*)((char*)hb + rw*640 + ((jp*4) ^ ((rw&7)<<4))) = pk;
  }
  __syncthreads();

  for (int t=0; t<steps; ++t){
    const char* hcur = (const char*)hb + (t&1)*10240;
    char* hnxt = (char*)hb + (((t&1)^1))*10240;
    const float* xr = Xih + (size_t)(row*steps + t)*NG;

#define ACT_PUB(ACC, CV, J)                                                        \
    {                                                                              \
      float hv0_, hv1_, hv2_, hv3_;                                                \
      { float c_ = sigm(ACC[1][0])*CV[0] + sigm(ACC[0][0])*tanhf_(ACC[2][0]);      \
        CV[0] = c_; hv0_ = sigm(ACC[3][0])*tanhf_(c_); }                           \
      { float c_ = sigm(ACC[1][1])*CV[1] + sigm(ACC[0][1])*tanhf_(ACC[2][1]);      \
        CV[1] = c_; hv1_ = sigm(ACC[3][1])*tanhf_(c_); }                           \
      { float c_ = sigm(ACC[1][2])*CV[2] + sigm(ACC[0][2])*tanhf_(ACC[2][2]);      \
        CV[2] = c_; hv2_ = sigm(ACC[3][2])*tanhf_(c_); }                           \
      { float c_ = sigm(ACC[1][3])*CV[3] + sigm(ACC[0][3])*tanhf_(ACC[2][3]);      \
        CV[3] = c_; hv3_ = sigm(ACC[3][3])*tanhf_(c_); }                           \
      if ((J) < EDIM){                                                             \
        uint2 q_;                                                                  \
        q_.x = (uint32_t)f2bf(hv0_) | ((uint32_t)f2bf(hv1_)<<16);                  \
        q_.y = (uint32_t)f2bf(hv2_) | ((uint32_t)f2bf(hv3_)<<16);                  \
        *(uint2*)(hnxt + l15*640 + (((J)*2) ^ ((l15&7)<<4))) = q_;                 \
        if (seq) *(uint2*)&seq[(size_t)(row*steps+t)*KPAD + (J)] = q_;             \
        if (t == steps-1 && hfin){                                                 \
          *(f32x4*)&hfin[row*EDIM + (J)] = (f32x4){hv0_,hv1_,hv2_,hv3_};           \
          *(f32x4*)&cfin[row*EDIM + (J)] = CV;                                     \
        }                                                                          \
      }                                                                            \
    }

    // ---- streamed slice (L2). unroll(2) bounds in-flight weight regs (~32).
    {
      int s = 11 + w;
      f32x4 acc[4];
      #pragma unroll
      for (int g=0; g<4; ++g) acc[g] = *(const f32x4*)&xr[g*EDIM + jS];
      const u16* wb = WA + (size_t)(s*40)*512 + lane*8;
      #pragma unroll 2
      for (int kc=0; kc<10; ++kc){
        bf16x8 hf = *(const bf16x8*)(hcur + l15*640 + (((kc*64) + lk*16) ^ ((l15&7)<<4)));
        #pragma unroll
        for (int g=0; g<4; ++g)
          acc[g] = __builtin_amdgcn_mfma_f32_16x16x32_bf16(
                     *(const bf16x8*)&wb[(size_t)(g*10+kc)*512], hf, acc[g], 0, 0, 0);
      }
      ACT_PUB(acc, cS, jS)
    }
    // ---- register-resident slice
    {
      f32x4 acc[4];
      #pragma unroll
      for (int g=0; g<4; ++g) acc[g] = *(const f32x4*)&xr[g*EDIM + jR];
      #pragma unroll
      for (int kc=0; kc<10; ++kc){
        bf16x8 hf = *(const bf16x8*)(hcur + l15*640 + (((kc*64) + lk*16) ^ ((l15&7)<<4)));
        #pragma unroll
        for (int g=0; g<4; ++g)
          acc[g] = __builtin_amdgcn_mfma_f32_16x16x32_bf16(wf[g][kc], hf, acc[g], 0, 0, 0);
      }
      ACT_PUB(acc, cR, jR)
    }
    // ---- LDS slice (waves 0..2)
    if (w < 3){
      f32x4 acc[4];
      #pragma unroll
      for (int g=0; g<4; ++g) acc[g] = *(const f32x4*)&xr[g*EDIM + jL];
      #pragma unroll 2
      for (int kc=0; kc<10; ++kc){
        bf16x8 hf = *(const bf16x8*)(hcur + l15*640 + (((kc*64) + lk*16) ^ ((l15&7)<<4)));
        #pragma unroll
        for (int g=0; g<4; ++g)
          acc[g] = __builtin_amdgcn_mfma_f32_16x16x32_bf16(
                     *(const bf16x8*)&wl[w][g][kc][lane*8], hf, acc[g], 0, 0, 0);
      }
      ACT_PUB(acc, cL, jL)
    }
#undef ACT_PUB
    __syncthreads();   // h(t) complete in hnxt before next step's reads
  }
}

// ---------------- fused log_softmax (in-place on d_out) + masked NLL ----------------
__global__ __launch_bounds__(256) void lsm_loss(float* __restrict__ out, const int* __restrict__ zh,
                                                float* __restrict__ lacc){
  int row = blockIdx.x;
  int tid = threadIdx.x;
  __shared__ float buf[ZHV];
  __shared__ float red[8];
  float* p = out + (size_t)row*ZHV;
  float m = -1e30f;
  for (int i=tid; i<ZHV; i+=256){ float v = p[i]; buf[i] = v; m = fmaxf(m, v); }
  for (int off=32; off; off>>=1) m = fmaxf(m, __shfl_xor(m, off));
  if ((tid&63)==0) red[tid>>6] = m;
  __syncthreads();
  m = fmaxf(fmaxf(red[0],red[1]), fmaxf(red[2],red[3]));
  float s = 0.f;
  for (int i=tid; i<ZHV; i+=256) s += __expf(buf[i]-m);
  for (int off=32; off; off>>=1) s += __shfl_xor(s, off);
  if ((tid&63)==0) red[4+(tid>>6)] = s;
  __syncthreads();
  s = red[4]+red[5]+red[6]+red[7];
  float lse = m + __logf(s);
  for (int i=tid; i<ZHV; i+=256) p[i] = buf[i] - lse;
  if (tid == 0){
    int b = row / SDEC, t = row - b*SDEC;
    int tgt = zh[b*SENC + t + 1];
    if (tgt != 0){
      atomicAdd(&lacc[0], -(buf[tgt] - lse));
      atomicAdd(&lacc[1], 1.0f);
    }
  }
}

__global__ void fin_loss(float* out, const float* lacc){
  out[(size_t)DROWS*ZHV] = lacc[0]/lacc[1];
}

// ---------------- host ----------------
extern "C" void kernel_launch(void* const* d_in, const int* in_sizes, int n_in,
                              void* d_out, int out_size, void* d_ws, size_t ws_size,
                              hipStream_t stream){
  const int*   en_in   = (const int*)d_in[0];
  const int*   zh_in   = (const int*)d_in[1];
  const float* en_emb  = (const float*)d_in[2];
  const float* zh_emb  = (const float*)d_in[3];
  const float* enc_Wih = (const float*)d_in[4];
  const float* enc_Whh = (const float*)d_in[5];
  const float* enc_b   = (const float*)d_in[6];
  const float* dec_Wih = (const float*)d_in[7];
  const float* dec_Whh = (const float*)d_in[8];
  const float* dec_b   = (const float*)d_in[9];
  const float* fc_W    = (const float*)d_in[10];
  const float* fc_b    = (const float*)d_in[11];
  float* out = (float*)d_out;
  char* ws = (char*)d_ws;

  size_t o = 0;
  auto alloc = [&](size_t b){ size_t r = o; o = (o + b + 255) & ~(size_t)255; return r; };
  size_t wa[4], wih[4];
  for (int i=0;i<4;i++) wa[i]  = alloc((size_t)20*4*10*512*2); // MFMA A-frag Whh bf16
  for (int i=0;i<4;i++) wih[i] = alloc((size_t)1280*KPAD*2);   // Wih as B operand
  size_t fcw  = alloc((size_t)12032*KPAD*2);
  size_t xen  = alloc((size_t)MPAD*KPAD*2);
  size_t xl1e = alloc((size_t)MPAD*KPAD*2);
  size_t xzh  = alloc((size_t)MPAD*KPAD*2);
  size_t xl1d = alloc((size_t)MPAD*KPAD*2);
  size_t xl2d = alloc((size_t)MPAD*KPAD*2);
  size_t xih  = alloc(((size_t)MPAD*NG + 64)*4);   // +64 floats: padded-slice overread
  size_t hfin = alloc((size_t)2*NB*EDIM*4);
  size_t cfin = alloc((size_t)2*NB*EDIM*4);
  size_t hz   = alloc((size_t)NB*EDIM*4 + 64);
  size_t lac  = alloc(256);
  size_t used = o;
  if (ws_size < used) return;  // fail loudly (output stays poisoned)

  zero_kernel<<<2048,256,0,stream>>>((float4*)ws, (long)(used/16));

  for (int l=0;l<2;l++){
    build_wa<<<1600,256,0,stream>>>(enc_Whh + (size_t)l*NG*EDIM, (u16*)(ws+wa[l]));
    build_wa<<<1600,256,0,stream>>>(dec_Whh + (size_t)l*NG*EDIM, (u16*)(ws+wa[2+l]));
    build_b<<<1407,256,0,stream>>>(enc_Wih + (size_t)l*NG*EDIM, (u16*)(ws+wih[l]),   NG);
    build_b<<<1407,256,0,stream>>>(dec_Wih + (size_t)l*NG*EDIM, (u16*)(ws+wih[2+l]), NG);
  }
  build_b<<<(ZHV*EDIM+255)/256,256,0,stream>>>(fc_W, (u16*)(ws+fcw), ZHV);
  embed_en<<<(MPAD*EDIM+255)/256,256,0,stream>>>(en_in, en_emb, (u16*)(ws+xen));
  embed_zh<<<(DROWS*EDIM+255)/256,256,0,stream>>>(zh_in, zh_emb, (u16*)(ws+xzh));

  float* XIH = (float*)(ws+xih);
  float* LAC = (float*)(ws+lac);
  float* HF  = (float*)(ws+hfin);
  float* CF  = (float*)(ws+cfin);
  float* HZ  = (float*)(ws+hz);

  // encoder layer 1  (LSTM bias folded into XIH via gemm bias)
  gemm_nt<<<dim3(10,32),256,0,stream>>>((u16*)(ws+xen), (u16*)(ws+wih[0]), XIH, NG, MPAD, NG, enc_b);
  recur_mix<<<4,512,0,stream>>>(XIH, (u16*)(ws+wa[0]), HZ, HZ, (u16*)(ws+xl1e), HF, CF, SENC);
  // encoder layer 2 (hidden sequence unused; only finals kept)
  gemm_nt<<<dim3(10,32),256,0,stream>>>((u16*)(ws+xl1e), (u16*)(ws+wih[1]), XIH, NG, MPAD, NG, enc_b+NG);
  recur_mix<<<4,512,0,stream>>>(XIH, (u16*)(ws+wa[1]), HZ, HZ, nullptr, HF+NB*EDIM, CF+NB*EDIM, SENC);
  // decoder layer 1
  gemm_nt<<<dim3(10,32),256,0,stream>>>((u16*)(ws+xzh), (u16*)(ws+wih[2]), XIH, NG, MPAD, NG, dec_b);
  recur_mix<<<4,512,0,stream>>>(XIH, (u16*)(ws+wa[2]), HF, CF, (u16*)(ws+xl1d), nullptr, nullptr, SDEC);
  // decoder layer 2
  gemm_nt<<<dim3(10,32),256,0,stream>>>((u16*)(ws+xl1d), (u16*)(ws+wih[3]), XIH, NG, MPAD, NG, dec_b+NG);
  recur_mix<<<4,512,0,stream>>>(XIH, (u16*)(ws+wa[3]), HF+NB*EDIM, CF+NB*EDIM, (u16*)(ws+xl2d), nullptr, nullptr, SDEC);
  // FC head -> logits straight into d_out
  gemm_nt<<<dim3(94,32),256,0,stream>>>((u16*)(ws+xl2d), (u16*)(ws+fcw), out, ZHV, DROWS, ZHV, fc_b);
  // in-place log_softmax + masked NLL
  lsm_loss<<<DROWS,256,0,stream>>>(out, zh_in, LAC);
  fin_loss<<<1,1,0,stream>>>(out, LAC);
}